// Round 1
// baseline (525.695 us; speedup 1.0000x reference)
//
#include <hip/hip_runtime.h>
#include <hip/hip_bf16.h>
#include <math.h>

#define NROWS 262144
#define NCOLS 256
#define G1    2048   // blocks for main pass (4 waves each -> 8192 waves, 32 rows/wave)
#define G7    1024   // blocks for classify pass
#define TIE_CAP 2048

struct Scal {
    double   sum_loss;
    double   sum_iv;
    float    mean_v;
    int      k;
    int      sel_hi;
    int      base_before;
    unsigned tau_key;
    int      need;
    int      cnt_below;
    int      tie_cnt;
};

__device__ __forceinline__ unsigned f2key(float f) {
    unsigned u = __float_as_uint(f);
    return (u & 0x80000000u) ? ~u : (u | 0x80000000u);
}

// ---------------- K0: zero scalars + histograms ----------------
__global__ void k_init(int* p, int n) {
    int i = blockIdx.x * blockDim.x + threadIdx.x;
    if (i < n) p[i] = 0;
}

// ---------------- K1: main pass, one wave per row ----------------
__global__ __launch_bounds__(256) void k_main(
    const float* __restrict__ y1, const float* __restrict__ y2,
    const int* __restrict__ t, const int* __restrict__ ep,
    float* __restrict__ loss, float* __restrict__ dcv,
    double* __restrict__ pb)
{
    const int lane = threadIdx.x & 63;
    const int wave = threadIdx.x >> 6;
    const int wavesTotal = (blockDim.x >> 6) * gridDim.x;
    const int gwave = blockIdx.x * (blockDim.x >> 6) + wave;

    const float fep   = (float)ep[0];
    const float expw  = 0.5f - 0.5f * fep / 200.0f;
    const float thresh = 1.0f - (1.0f - fminf(0.5f, 1.0f / (float)NROWS)) * fep / 200.0f;

    double acc_loss = 0.0, acc_iv = 0.0;

    for (int row = gwave; row < NROWS; row += wavesTotal) {
        const float4 a = reinterpret_cast<const float4*>(y1 + (size_t)row * NCOLS)[lane];
        const float4 b = reinterpret_cast<const float4*>(y2 + (size_t)row * NCOLS)[lane];
        const float va0 = a.x, va1 = a.y, va2 = a.z, va3 = a.w;
        const float vb0 = b.x, vb1 = b.y, vb2 = b.z, vb3 = b.w;

        // local argmax (first occurrence => strict >)
        float m1 = va0; int i1 = lane * 4;
        if (va1 > m1) { m1 = va1; i1 = lane * 4 + 1; }
        if (va2 > m1) { m1 = va2; i1 = lane * 4 + 2; }
        if (va3 > m1) { m1 = va3; i1 = lane * 4 + 3; }
        float m2 = vb0; int i2 = lane * 4;
        if (vb1 > m2) { m2 = vb1; i2 = lane * 4 + 1; }
        if (vb2 > m2) { m2 = vb2; i2 = lane * 4 + 2; }
        if (vb3 > m2) { m2 = vb3; i2 = lane * 4 + 3; }

        #pragma unroll
        for (int mask = 1; mask < 64; mask <<= 1) {
            float om = __shfl_xor(m1, mask); int oi = __shfl_xor(i1, mask);
            if (om > m1 || (om == m1 && oi < i1)) { m1 = om; i1 = oi; }
            float pm = __shfl_xor(m2, mask); int pi = __shfl_xor(i2, mask);
            if (pm > m2 || (pm == m2 && pi < i2)) { m2 = pm; i2 = pi; }
        }

        // exp sums + cross sums
        const float e10 = __expf(va0 - m1), e11 = __expf(va1 - m1);
        const float e12 = __expf(va2 - m1), e13 = __expf(va3 - m1);
        const float e20 = __expf(vb0 - m2), e21 = __expf(vb1 - m2);
        const float e22 = __expf(vb2 - m2), e23 = __expf(vb3 - m2);
        float z1 = e10 + e11 + e12 + e13;
        float z2 = e20 + e21 + e22 + e23;
        float A = e10 * (va0 - vb0) + e11 * (va1 - vb1) + e12 * (va2 - vb2) + e13 * (va3 - vb3);
        float B = e20 * (vb0 - va0) + e21 * (vb1 - va1) + e22 * (vb2 - va2) + e23 * (vb3 - va3);
        #pragma unroll
        for (int mask = 1; mask < 64; mask <<= 1) {
            z1 += __shfl_xor(z1, mask);
            z2 += __shfl_xor(z2, mask);
            A  += __shfl_xor(A,  mask);
            B  += __shfl_xor(B,  mask);
        }

        // gather y1[t], y2[t]
        const int tc = t[row];
        const int te = tc & 3, tl = tc >> 2;
        float y1c = (te == 1) ? va1 : (te == 2) ? va2 : (te == 3) ? va3 : va0;
        float y2c = (te == 1) ? vb1 : (te == 2) ? vb2 : (te == 3) ? vb3 : vb0;
        const float y1t = __shfl(y1c, tl);
        const float y2t = __shfl(y2c, tl);

        // gather y2[pred1]
        const int pe = i1 & 3, pl = i1 >> 2;
        float y2pc = (pe == 1) ? vb1 : (pe == 2) ? vb2 : (pe == 3) ? vb3 : vb0;
        const float y2p = __shfl(y2pc, pl);

        const float lz1 = __logf(z1), lz2 = __logf(z2);
        const float lse1 = m1 + lz1, lse2 = m2 + lz2;
        const float lp = (lse1 - y1t) + (lse2 - y2t);          // loss_pick
        const float pp = 1.0f / (z1 * z2);                     // pmax1*pmax2
        const bool cond = (i1 != tc) && (i1 == i2) && (pp > thresh);
        const float wgt = __powf(pp, expw);
        const float cedc = lz1 + (lse2 - y2p);                 // -logp1[pred1]-logp2[pred1]
        const float dv = cond ? fmaxf(wgt * cedc, 0.0f) : -1.0f;
        const float iv = A / z1 + B / z2;                      // kl12+kl21 per row

        if (lane == 0) {
            loss[row] = lp;
            dcv[row]  = dv;
            acc_loss += (double)lp;
            acc_iv   += (double)iv;
        }
    }

    __shared__ double sl[4], si[4];
    if (lane == 0) { sl[wave] = acc_loss; si[wave] = acc_iv; }
    __syncthreads();
    if (threadIdx.x == 0) {
        pb[blockIdx.x * 2 + 0] = sl[0] + sl[1] + sl[2] + sl[3];
        pb[blockIdx.x * 2 + 1] = si[0] + si[1] + si[2] + si[3];
    }
}

// ---------------- K2: reduce block partials -> sums, mean ----------------
__global__ void k_reduce_pb(const double* __restrict__ pb, Scal* sc) {
    __shared__ double s1[256], s2[256];
    int th = threadIdx.x;
    double a = 0.0, b = 0.0;
    for (int i = th; i < G1; i += 256) { a += pb[i * 2]; b += pb[i * 2 + 1]; }
    s1[th] = a; s2[th] = b; __syncthreads();
    for (int off = 128; off; off >>= 1) {
        if (th < off) { s1[th] += s1[th + off]; s2[th] += s2[th + off]; }
        __syncthreads();
    }
    if (th == 0) {
        sc->sum_loss = s1[0];
        sc->sum_iv   = s2[0];
        sc->mean_v   = (float)(s1[0] / (double)NROWS);
    }
}

// ---------------- K3: count below mean + high-16 histogram ----------------
__global__ __launch_bounds__(256) void k_hist1(const float* __restrict__ loss, Scal* sc, int* __restrict__ hist1) {
    int i = blockIdx.x * blockDim.x + threadIdx.x;
    float v = loss[i];
    unsigned long long m = __ballot(v < sc->mean_v);
    if ((threadIdx.x & 63) == 0) atomicAdd(&sc->cnt_below, __popcll(m));
    unsigned key = f2key(v);
    atomicAdd(&hist1[key >> 16], 1);
}

// ---------------- K4: find hi bin containing rank k ----------------
__global__ void k_select_hi(const int* __restrict__ hist, Scal* sc, const int* __restrict__ ep) {
    __shared__ int part[256];
    __shared__ int pref[257];
    __shared__ int k_sh;
    int th = threadIdx.x;
    if (th == 0) {
        float rrs = (float)sc->cnt_below / (float)NROWS;
        float rr = fmaxf(1.0f - (0.5f / 200.0f) * (float)ep[0], rrs);
        int k = (int)floorf(rr * (float)NROWS);
        if (k < 1) k = 1;
        if (k > NROWS) k = NROWS;
        k_sh = k; sc->k = k;
    }
    __syncthreads();
    int s = 0;
    for (int b = 0; b < 256; b++) s += hist[th * 256 + b];
    part[th] = s;
    __syncthreads();
    if (th == 0) { int c = 0; for (int i = 0; i < 256; i++) { pref[i] = c; c += part[i]; } pref[256] = c; }
    __syncthreads();
    int k = k_sh;
    if (pref[th] < k && k <= pref[th] + part[th]) {
        int c = pref[th];
        for (int b = 0; b < 256; b++) {
            int h = hist[th * 256 + b];
            if (c + h >= k) { sc->sel_hi = th * 256 + b; sc->base_before = c; break; }
            c += h;
        }
    }
}

// ---------------- K5: low-16 histogram within selected hi bin ----------------
__global__ __launch_bounds__(256) void k_hist2(const float* __restrict__ loss, const Scal* sc, int* __restrict__ hist2) {
    int i = blockIdx.x * blockDim.x + threadIdx.x;
    unsigned key = f2key(loss[i]);
    if ((int)(key >> 16) == sc->sel_hi) atomicAdd(&hist2[key & 0xFFFFu], 1);
}

// ---------------- K6: find exact tau key + need ----------------
__global__ void k_select_lo(const int* __restrict__ hist2, Scal* sc) {
    __shared__ int part[256];
    __shared__ int pref[257];
    int th = threadIdx.x;
    int r = sc->k - sc->base_before;   // 1-based rank within bin
    int s = 0;
    for (int b = 0; b < 256; b++) s += hist2[th * 256 + b];
    part[th] = s;
    __syncthreads();
    if (th == 0) { int c = 0; for (int i = 0; i < 256; i++) { pref[i] = c; c += part[i]; } pref[256] = c; }
    __syncthreads();
    if (pref[th] < r && r <= pref[th] + part[th]) {
        int c = pref[th];
        for (int b = 0; b < 256; b++) {
            int h = hist2[th * 256 + b];
            if (c + h >= r) {
                sc->tau_key = ((unsigned)sc->sel_hi << 16) | (unsigned)(th * 256 + b);
                sc->need = r - c;   // number of tie rows that are remembered
                break;
            }
            c += h;
        }
    }
}

// ---------------- K7: classify rows, per-block double partials ----------------
__global__ __launch_bounds__(256) void k_classify(
    const float* __restrict__ loss, const float* __restrict__ dcv,
    Scal* sc, int* __restrict__ tiebuf, double* __restrict__ pc)
{
    __shared__ double s0[256], s1v[256], s2v[256];
    int th = threadIdx.x;
    unsigned tk = sc->tau_key;
    double cl = 0.0, cd = 0.0, c1 = 0.0;
    for (int i = blockIdx.x * blockDim.x + th; i < NROWS; i += blockDim.x * gridDim.x) {
        float lp = loss[i];
        unsigned key = f2key(lp);
        if (key < tk) {
            cl += (double)lp;                       // remembered
        } else if (key > tk) {
            if (i != 0) {
                float d = dcv[i];
                if (d >= 0.0f) cd += (double)d;     // dc subset
                else           c1 += (double)lp;    // remain subset
            }
        } else {
            int slot = atomicAdd(&sc->tie_cnt, 1);
            if (slot < TIE_CAP) tiebuf[slot] = i;
        }
    }
    s0[th] = cl; s1v[th] = cd; s2v[th] = c1;
    __syncthreads();
    for (int off = 128; off; off >>= 1) {
        if (th < off) { s0[th] += s0[th + off]; s1v[th] += s1v[th + off]; s2v[th] += s2v[th + off]; }
        __syncthreads();
    }
    if (th == 0) {
        pc[blockIdx.x * 3 + 0] = s0[0];
        pc[blockIdx.x * 3 + 1] = s1v[0];
        pc[blockIdx.x * 3 + 2] = s2v[0];
    }
}

// ---------------- K8: final reduce + tie resolution + output ----------------
__global__ void k_final(const double* __restrict__ pc,
                        const float* __restrict__ loss, const float* __restrict__ dcv,
                        Scal* sc, int* __restrict__ tiebuf, float* __restrict__ out)
{
    __shared__ double s0[256], s1v[256], s2v[256];
    int th = threadIdx.x;
    double a = 0.0, b = 0.0, c = 0.0;
    for (int i = th; i < G7; i += 256) { a += pc[i * 3]; b += pc[i * 3 + 1]; c += pc[i * 3 + 2]; }
    s0[th] = a; s1v[th] = b; s2v[th] = c;
    __syncthreads();
    for (int off = 128; off; off >>= 1) {
        if (th < off) { s0[th] += s0[th + off]; s1v[th] += s1v[th + off]; s2v[th] += s2v[th + off]; }
        __syncthreads();
    }
    if (th == 0) {
        double sum_clean = s0[0], sum_dc = s1v[0], sum_1 = s2v[0];
        int nt = sc->tie_cnt;
        if (nt > TIE_CAP) nt = TIE_CAP;
        // stable: sort tie indices ascending (matches stable argsort rank order)
        for (int i = 1; i < nt; i++) {
            int v = tiebuf[i]; int j = i - 1;
            while (j >= 0 && tiebuf[j] > v) { tiebuf[j + 1] = tiebuf[j]; j--; }
            tiebuf[j + 1] = v;
        }
        int need = sc->need;
        for (int s = 0; s < nt; s++) {
            int idx = tiebuf[s];
            float lp = loss[idx];
            if (s < need) {
                sum_clean += (double)lp;            // remembered ties: smallest indices
            } else if (idx != 0) {
                float d = dcv[idx];
                if (d >= 0.0f) sum_dc += (double)d;
                else           sum_1 += (double)lp;
            }
        }
        double invN = 1.0 / (double)NROWS;
        out[0] = (float)((sum_clean + sum_dc + sum_1) * invN + 0.1 * sc->sum_iv * invN);
    }
}

extern "C" void kernel_launch(void* const* d_in, const int* in_sizes, int n_in,
                              void* d_out, int out_size, void* d_ws, size_t ws_size,
                              hipStream_t stream) {
    const float* y1 = (const float*)d_in[0];
    const float* y2 = (const float*)d_in[1];
    const int*   t  = (const int*)d_in[2];
    const int*   ep = (const int*)d_in[3];
    float* out = (float*)d_out;

    char* w = (char*)d_ws;
    Scal*   sc     = (Scal*)w;
    int*    hist1  = (int*)(w + 256);
    int*    hist2  = (int*)(w + 256 + 65536 * 4);
    float*  loss   = (float*)(w + 256 + 65536 * 8);
    float*  dcv    = (float*)(w + 256 + 65536 * 8 + NROWS * 4);
    double* pb     = (double*)(w + 256 + 65536 * 8 + NROWS * 8);
    double* pc     = (double*)(w + 256 + 65536 * 8 + NROWS * 8 + G1 * 16);
    int*    tiebuf = (int*)(w + 256 + 65536 * 8 + NROWS * 8 + G1 * 16 + G7 * 24);

    // zero Scal + both histograms (contiguous at ws start)
    const int nzero = (256 + 65536 * 8) / 4;
    k_init<<<(nzero + 255) / 256, 256, 0, stream>>>((int*)d_ws, nzero);

    k_main<<<G1, 256, 0, stream>>>(y1, y2, t, ep, loss, dcv, pb);
    k_reduce_pb<<<1, 256, 0, stream>>>(pb, sc);
    k_hist1<<<NROWS / 256, 256, 0, stream>>>(loss, sc, hist1);
    k_select_hi<<<1, 256, 0, stream>>>(hist1, sc, ep);
    k_hist2<<<NROWS / 256, 256, 0, stream>>>(loss, sc, hist2);
    k_select_lo<<<1, 256, 0, stream>>>(hist2, sc);
    k_classify<<<G7, 256, 0, stream>>>(loss, dcv, sc, tiebuf, pc);
    k_final<<<1, 256, 0, stream>>>(pc, loss, dcv, sc, tiebuf, out);
}

// Round 2
// 245.325 us; speedup vs baseline: 2.1428x; 2.1428x over previous
//
#include <hip/hip_runtime.h>
#include <hip/hip_bf16.h>
#include <math.h>

#define NROWS 262144
#define NCOLS 256
#define G1    2048   // blocks for main pass (4 waves each -> 8192 waves, 32 rows/wave)
#define G3    512    // blocks for hist passes (x256 thr x2 elems)
#define G7    1024   // blocks for classify pass
#define TIE_CAP 2048

struct Scal {
    double   sum_loss;
    double   sum_iv;
    float    mean_v;
    int      cnt_below;
    int      rank;
    int      sel_a;
    int      sel_b;
    unsigned tau_key;
    int      need;
    int      tie_cnt;
};

__device__ __forceinline__ unsigned f2key(float f) {
    unsigned u = __float_as_uint(f);
    return (u & 0x80000000u) ? ~u : (u | 0x80000000u);
}

// ---------------- K0: zero scalars + histograms ----------------
__global__ void k_init(int* p, int n) {
    int i = blockIdx.x * blockDim.x + threadIdx.x;
    if (i < n) p[i] = 0;
}

// ---------------- K1: main pass, one wave per row ----------------
__global__ __launch_bounds__(256) void k_main(
    const float* __restrict__ y1, const float* __restrict__ y2,
    const int* __restrict__ t, const int* __restrict__ ep,
    float* __restrict__ loss, float* __restrict__ dcv,
    double* __restrict__ pb)
{
    const int lane = threadIdx.x & 63;
    const int wave = threadIdx.x >> 6;
    const int wavesTotal = (blockDim.x >> 6) * gridDim.x;
    const int gwave = blockIdx.x * (blockDim.x >> 6) + wave;

    const float fep   = (float)ep[0];
    const float expw  = 0.5f - 0.5f * fep / 200.0f;
    const float thresh = 1.0f - (1.0f - fminf(0.5f, 1.0f / (float)NROWS)) * fep / 200.0f;

    double acc_loss = 0.0, acc_iv = 0.0;

    for (int row = gwave; row < NROWS; row += wavesTotal) {
        const float4 a = reinterpret_cast<const float4*>(y1 + (size_t)row * NCOLS)[lane];
        const float4 b = reinterpret_cast<const float4*>(y2 + (size_t)row * NCOLS)[lane];
        const float va0 = a.x, va1 = a.y, va2 = a.z, va3 = a.w;
        const float vb0 = b.x, vb1 = b.y, vb2 = b.z, vb3 = b.w;

        // local argmax (first occurrence => strict >)
        float m1 = va0; int i1 = lane * 4;
        if (va1 > m1) { m1 = va1; i1 = lane * 4 + 1; }
        if (va2 > m1) { m1 = va2; i1 = lane * 4 + 2; }
        if (va3 > m1) { m1 = va3; i1 = lane * 4 + 3; }
        float m2 = vb0; int i2 = lane * 4;
        if (vb1 > m2) { m2 = vb1; i2 = lane * 4 + 1; }
        if (vb2 > m2) { m2 = vb2; i2 = lane * 4 + 2; }
        if (vb3 > m2) { m2 = vb3; i2 = lane * 4 + 3; }

        #pragma unroll
        for (int mask = 1; mask < 64; mask <<= 1) {
            float om = __shfl_xor(m1, mask); int oi = __shfl_xor(i1, mask);
            if (om > m1 || (om == m1 && oi < i1)) { m1 = om; i1 = oi; }
            float pm = __shfl_xor(m2, mask); int pi = __shfl_xor(i2, mask);
            if (pm > m2 || (pm == m2 && pi < i2)) { m2 = pm; i2 = pi; }
        }

        // exp sums + cross sums
        const float e10 = __expf(va0 - m1), e11 = __expf(va1 - m1);
        const float e12 = __expf(va2 - m1), e13 = __expf(va3 - m1);
        const float e20 = __expf(vb0 - m2), e21 = __expf(vb1 - m2);
        const float e22 = __expf(vb2 - m2), e23 = __expf(vb3 - m2);
        float z1 = e10 + e11 + e12 + e13;
        float z2 = e20 + e21 + e22 + e23;
        float A = e10 * (va0 - vb0) + e11 * (va1 - vb1) + e12 * (va2 - vb2) + e13 * (va3 - vb3);
        float B = e20 * (vb0 - va0) + e21 * (vb1 - va1) + e22 * (vb2 - va2) + e23 * (vb3 - va3);
        #pragma unroll
        for (int mask = 1; mask < 64; mask <<= 1) {
            z1 += __shfl_xor(z1, mask);
            z2 += __shfl_xor(z2, mask);
            A  += __shfl_xor(A,  mask);
            B  += __shfl_xor(B,  mask);
        }

        // gather y1[t], y2[t]
        const int tc = t[row];
        const int te = tc & 3, tl = tc >> 2;
        float y1c = (te == 1) ? va1 : (te == 2) ? va2 : (te == 3) ? va3 : va0;
        float y2c = (te == 1) ? vb1 : (te == 2) ? vb2 : (te == 3) ? vb3 : vb0;
        const float y1t = __shfl(y1c, tl);
        const float y2t = __shfl(y2c, tl);

        // gather y2[pred1]
        const int pe = i1 & 3, pl = i1 >> 2;
        float y2pc = (pe == 1) ? vb1 : (pe == 2) ? vb2 : (pe == 3) ? vb3 : vb0;
        const float y2p = __shfl(y2pc, pl);

        const float lz1 = __logf(z1), lz2 = __logf(z2);
        const float lse1 = m1 + lz1, lse2 = m2 + lz2;
        const float lp = (lse1 - y1t) + (lse2 - y2t);          // loss_pick
        const float pp = 1.0f / (z1 * z2);                     // pmax1*pmax2
        const bool cond = (i1 != tc) && (i1 == i2) && (pp > thresh);
        const float wgt = __powf(pp, expw);
        const float cedc = lz1 + (lse2 - y2p);                 // -logp1[pred1]-logp2[pred1]
        const float dv = cond ? fmaxf(wgt * cedc, 0.0f) : -1.0f;
        const float iv = A / z1 + B / z2;                      // kl12+kl21 per row

        if (lane == 0) {
            loss[row] = lp;
            dcv[row]  = dv;
            acc_loss += (double)lp;
            acc_iv   += (double)iv;
        }
    }

    __shared__ double sl[4], si[4];
    if (lane == 0) { sl[wave] = acc_loss; si[wave] = acc_iv; }
    __syncthreads();
    if (threadIdx.x == 0) {
        pb[blockIdx.x * 2 + 0] = sl[0] + sl[1] + sl[2] + sl[3];
        pb[blockIdx.x * 2 + 1] = si[0] + si[1] + si[2] + si[3];
    }
}

// ---------------- K2: reduce block partials -> sums, mean ----------------
__global__ void k_reduce_pb(const double* __restrict__ pb, Scal* sc) {
    __shared__ double s1[256], s2[256];
    int th = threadIdx.x;
    double a = 0.0, b = 0.0;
    for (int i = th; i < G1; i += 256) { a += pb[i * 2]; b += pb[i * 2 + 1]; }
    s1[th] = a; s2[th] = b; __syncthreads();
    for (int off = 128; off; off >>= 1) {
        if (th < off) { s1[th] += s1[th + off]; s2[th] += s2[th + off]; }
        __syncthreads();
    }
    if (th == 0) {
        sc->sum_loss = s1[0];
        sc->sum_iv   = s2[0];
        sc->mean_v   = (float)(s1[0] / (double)NROWS);
    }
}

// ---------------- K3: cnt_below + level-A hist (hi-11 bits), LDS-privatized ----
__global__ __launch_bounds__(256) void k_histA(const float* __restrict__ loss,
                                               Scal* sc, int* __restrict__ histA) {
    __shared__ int lh[2048];
    __shared__ int cbel;
    int th = threadIdx.x;
    for (int i = th; i < 2048; i += 256) lh[i] = 0;
    if (th == 0) cbel = 0;
    __syncthreads();
    const float mv = sc->mean_v;
    int stride = G3 * 256;
    for (int i = blockIdx.x * 256 + th; i < NROWS; i += stride) {
        float v = loss[i];
        unsigned long long m = __ballot(v < mv);
        if ((th & 63) == 0) atomicAdd(&cbel, __popcll(m));
        atomicAdd(&lh[f2key(v) >> 21], 1);
    }
    __syncthreads();
    if (th == 0 && cbel) atomicAdd(&sc->cnt_below, cbel);
    for (int i = th; i < 2048; i += 256) {
        int v = lh[i];
        if (v) atomicAdd(&histA[i], v);
    }
}

// ---------------- K5: level-B hist (bits 20:10) within selected A bin ----------
__global__ __launch_bounds__(256) void k_histB(const float* __restrict__ loss,
                                               const Scal* __restrict__ sc,
                                               int* __restrict__ histB) {
    __shared__ int lh[2048];
    int th = threadIdx.x;
    for (int i = th; i < 2048; i += 256) lh[i] = 0;
    __syncthreads();
    const unsigned a = (unsigned)sc->sel_a;
    int stride = G3 * 256;
    for (int i = blockIdx.x * 256 + th; i < NROWS; i += stride) {
        unsigned key = f2key(loss[i]);
        if ((key >> 21) == a) atomicAdd(&lh[(key >> 10) & 0x7FFu], 1);
    }
    __syncthreads();
    for (int i = th; i < 2048; i += 256) {
        int v = lh[i];
        if (v) atomicAdd(&histB[i], v);
    }
}

// ---------------- K7: level-C hist (bits 9:0) within selected A,B bins --------
__global__ __launch_bounds__(256) void k_histC(const float* __restrict__ loss,
                                               const Scal* __restrict__ sc,
                                               int* __restrict__ histC) {
    __shared__ int lh[1024];
    int th = threadIdx.x;
    for (int i = th; i < 1024; i += 256) lh[i] = 0;
    __syncthreads();
    const unsigned ab = ((unsigned)sc->sel_a << 11) | (unsigned)sc->sel_b;
    int stride = G3 * 256;
    for (int i = blockIdx.x * 256 + th; i < NROWS; i += stride) {
        unsigned key = f2key(loss[i]);
        if ((key >> 10) == ab) atomicAdd(&lh[key & 0x3FFu], 1);
    }
    __syncthreads();
    for (int i = th; i < 1024; i += 256) {
        int v = lh[i];
        if (v) atomicAdd(&histC[i], v);
    }
}

// ---------------- K4/K6/K8: select bin containing current rank ----------------
__global__ void k_select(const int* __restrict__ hist, Scal* sc,
                         const int* __restrict__ ep, int nbins, int stage) {
    __shared__ int part[256];
    __shared__ int pref[256];
    __shared__ int rank_sh;
    int th = threadIdx.x;
    int bpt = nbins >> 8;
    if (th == 0) {
        int r;
        if (stage == 0) {
            float rrs = (float)sc->cnt_below / (float)NROWS;
            float rr = fmaxf(1.0f - 0.0025f * (float)ep[0], rrs);
            int k = (int)floorf(rr * (float)NROWS);
            if (k < 1) k = 1;
            if (k > NROWS) k = NROWS;
            r = k;
        } else {
            r = sc->rank;
        }
        rank_sh = r;
    }
    __syncthreads();
    int s = 0;
    for (int b = 0; b < bpt; b++) s += hist[th * bpt + b];
    part[th] = s;
    __syncthreads();
    if (th == 0) { int c = 0; for (int i = 0; i < 256; i++) { pref[i] = c; c += part[i]; } }
    __syncthreads();
    int r = rank_sh;
    if (pref[th] < r && r <= pref[th] + part[th]) {
        int c = pref[th];
        for (int b = 0; b < bpt; b++) {
            int h = hist[th * bpt + b];
            if (c + h >= r) {
                int bin = th * bpt + b;
                if (stage == 0)      { sc->sel_a = bin; sc->rank = r - c; }
                else if (stage == 1) { sc->sel_b = bin; sc->rank = r - c; }
                else {
                    sc->tau_key = ((unsigned)sc->sel_a << 21) |
                                  ((unsigned)sc->sel_b << 10) | (unsigned)bin;
                    sc->need = r - c;
                }
                break;
            }
            c += h;
        }
    }
}

// ---------------- K9: classify rows, per-block double partials ----------------
__global__ __launch_bounds__(256) void k_classify(
    const float* __restrict__ loss, const float* __restrict__ dcv,
    Scal* sc, int* __restrict__ tiebuf, double* __restrict__ pc)
{
    __shared__ double s0[256], s1v[256], s2v[256];
    int th = threadIdx.x;
    unsigned tk = sc->tau_key;
    double cl = 0.0, cd = 0.0, c1 = 0.0;
    for (int i = blockIdx.x * blockDim.x + th; i < NROWS; i += blockDim.x * gridDim.x) {
        float lp = loss[i];
        unsigned key = f2key(lp);
        if (key < tk) {
            cl += (double)lp;                       // remembered
        } else if (key > tk) {
            if (i != 0) {
                float d = dcv[i];
                if (d >= 0.0f) cd += (double)d;     // dc subset
                else           c1 += (double)lp;    // remain subset
            }
        } else {
            int slot = atomicAdd(&sc->tie_cnt, 1);
            if (slot < TIE_CAP) tiebuf[slot] = i;
        }
    }
    s0[th] = cl; s1v[th] = cd; s2v[th] = c1;
    __syncthreads();
    for (int off = 128; off; off >>= 1) {
        if (th < off) { s0[th] += s0[th + off]; s1v[th] += s1v[th + off]; s2v[th] += s2v[th + off]; }
        __syncthreads();
    }
    if (th == 0) {
        pc[blockIdx.x * 3 + 0] = s0[0];
        pc[blockIdx.x * 3 + 1] = s1v[0];
        pc[blockIdx.x * 3 + 2] = s2v[0];
    }
}

// ---------------- K10: final reduce + tie resolution + output ----------------
__global__ void k_final(const double* __restrict__ pc,
                        const float* __restrict__ loss, const float* __restrict__ dcv,
                        Scal* sc, int* __restrict__ tiebuf, float* __restrict__ out)
{
    __shared__ double s0[256], s1v[256], s2v[256];
    int th = threadIdx.x;
    double a = 0.0, b = 0.0, c = 0.0;
    for (int i = th; i < G7; i += 256) { a += pc[i * 3]; b += pc[i * 3 + 1]; c += pc[i * 3 + 2]; }
    s0[th] = a; s1v[th] = b; s2v[th] = c;
    __syncthreads();
    for (int off = 128; off; off >>= 1) {
        if (th < off) { s0[th] += s0[th + off]; s1v[th] += s1v[th + off]; s2v[th] += s2v[th + off]; }
        __syncthreads();
    }
    if (th == 0) {
        double sum_clean = s0[0], sum_dc = s1v[0], sum_1 = s2v[0];
        int nt = sc->tie_cnt;
        if (nt > TIE_CAP) nt = TIE_CAP;
        // stable: sort tie indices ascending (matches stable argsort rank order)
        for (int i = 1; i < nt; i++) {
            int v = tiebuf[i]; int j = i - 1;
            while (j >= 0 && tiebuf[j] > v) { tiebuf[j + 1] = tiebuf[j]; j--; }
            tiebuf[j + 1] = v;
        }
        int need = sc->need;
        for (int s = 0; s < nt; s++) {
            int idx = tiebuf[s];
            float lp = loss[idx];
            if (s < need) {
                sum_clean += (double)lp;            // remembered ties: smallest indices
            } else if (idx != 0) {
                float d = dcv[idx];
                if (d >= 0.0f) sum_dc += (double)d;
                else           sum_1 += (double)lp;
            }
        }
        double invN = 1.0 / (double)NROWS;
        out[0] = (float)((sum_clean + sum_dc + sum_1) * invN + 0.1 * sc->sum_iv * invN);
    }
}

extern "C" void kernel_launch(void* const* d_in, const int* in_sizes, int n_in,
                              void* d_out, int out_size, void* d_ws, size_t ws_size,
                              hipStream_t stream) {
    const float* y1 = (const float*)d_in[0];
    const float* y2 = (const float*)d_in[1];
    const int*   t  = (const int*)d_in[2];
    const int*   ep = (const int*)d_in[3];
    float* out = (float*)d_out;

    char* w = (char*)d_ws;
    Scal*   sc     = (Scal*)w;                       // 256 B (padded)
    int*    histA  = (int*)(w + 256);                // 2048 ints
    int*    histB  = (int*)(w + 256 + 8192);         // 2048 ints
    int*    histC  = (int*)(w + 256 + 16384);        // 1024 ints
    float*  loss   = (float*)(w + 256 + 20480);
    float*  dcv    = (float*)(w + 256 + 20480 + NROWS * 4);
    double* pb     = (double*)(w + 256 + 20480 + NROWS * 8);
    double* pc     = (double*)(w + 256 + 20480 + NROWS * 8 + G1 * 16);
    int*    tiebuf = (int*)(w + 256 + 20480 + NROWS * 8 + G1 * 16 + G7 * 24);

    // zero Scal + all three histograms (contiguous at ws start)
    const int nzero = (256 + 20480) / 4;
    k_init<<<(nzero + 255) / 256, 256, 0, stream>>>((int*)d_ws, nzero);

    k_main<<<G1, 256, 0, stream>>>(y1, y2, t, ep, loss, dcv, pb);
    k_reduce_pb<<<1, 256, 0, stream>>>(pb, sc);
    k_histA<<<G3, 256, 0, stream>>>(loss, sc, histA);
    k_select<<<1, 256, 0, stream>>>(histA, sc, ep, 2048, 0);
    k_histB<<<G3, 256, 0, stream>>>(loss, sc, histB);
    k_select<<<1, 256, 0, stream>>>(histB, sc, ep, 2048, 1);
    k_histC<<<G3, 256, 0, stream>>>(loss, sc, histC);
    k_select<<<1, 256, 0, stream>>>(histC, sc, ep, 1024, 2);
    k_classify<<<G7, 256, 0, stream>>>(loss, dcv, sc, tiebuf, pc);
    k_final<<<1, 256, 0, stream>>>(pc, loss, dcv, sc, tiebuf, out);
}